// Round 7
// baseline (1828.833 us; speedup 1.0000x reference)
//
#include <hip/hip_runtime.h>
#include <cstdint>
#include <cstddef>

// ----------------------------------------------------------------------------
// R7: latency-hiding pass. 2-phase pipelined convt_mfma (reg-staged A prefetch,
// LDS double-buffer, lgkm-only barrier so prefetch loads fly across it),
// lighter register blocking (MFR=2 everywhere), BN+tanh fused into conv4,
// wave-per-row topk. Workspace layout identical to R6 (proven <=135,073,792).
//   y2   @ 0           64MB  [2048][64][256] bf16
//   y1   @ 67108864    32MB  [2048][16][512] bf16   (dead after conv2)
//   w3t  @ 67108864    1MB   [128][16][256]  bf16   (written after conv2)
//   y3c  @ 100663296   32MB  [2048][256][32] bf16   (written at conv3)
//   w1t  @ 100663296   16MB  (dead after conv1)
//   w2t  @ 117047296   4MB   (dead after conv2)
//   vals @ 134217728, idxs @ 134627328 (dead after conv1)
//   sp   @ 134217728, sqp @ 134479872, ac @ 134742016, bc @ 134744064
// ----------------------------------------------------------------------------

typedef unsigned short u16;
typedef unsigned int u32;
typedef __attribute__((ext_vector_type(8))) short s16x8;   // 8 bf16 (4 VGPR)
typedef __attribute__((ext_vector_type(4))) float f32x4;

static __device__ __forceinline__ float bf2f(u16 u) {
  union { u32 i; float f; } v; v.i = ((u32)u) << 16; return v.f;
}
static __device__ __forceinline__ u16 f2bf(float f) {  // RNE
  union { float f; u32 i; } v; v.f = f;
  const u32 r = v.i + 0x7fffu + ((v.i >> 16) & 1u);
  return (u16)(r >> 16);
}
// barrier that waits only LDS ops -> prefetch global loads stay in flight
static __device__ __forceinline__ void lds_barrier() {
  asm volatile("s_waitcnt lgkmcnt(0)" ::: "memory");
  __builtin_amdgcn_s_barrier();
}

// ---------------- top-k(50): one wave per row, all in registers -------------
__global__ __launch_bounds__(256) void topk_kernel(const float* __restrict__ x,
                                                   float* __restrict__ vals,
                                                   int* __restrict__ idxs) {
  const int lane = threadIdx.x & 63;
  const int b = blockIdx.x * 4 + (threadIdx.x >> 6);
  float v[16];
  #pragma unroll
  for (int j = 0; j < 16; ++j) {
    const int idx = lane + 64 * j;
    v[j] = (idx < 1000) ? x[(size_t)b * 1000 + idx] : -INFINITY;
  }
  float keepv = 1.0f;
  int keepi = 0;
  for (int k = 0; k < 50; ++k) {
    float bv = v[0]; int bj = 0;
    #pragma unroll
    for (int j = 1; j < 16; ++j)
      if (v[j] > bv) { bv = v[j]; bj = j; }   // strict > keeps lowest idx in-lane
    int bi = lane + 64 * bj;
    #pragma unroll
    for (int off = 1; off < 64; off <<= 1) {
      const float ov = __shfl_xor(bv, off);
      const int oi = __shfl_xor(bi, off);
      if (ov > bv || (ov == bv && oi < bi)) { bv = ov; bi = oi; }
    }
    // all lanes agree on (bv, bi); owner clears its slot (static indexing only)
    const int slot = bi >> 6;
    const bool own = (lane == (bi & 63));
    #pragma unroll
    for (int j = 0; j < 16; ++j)
      if (own && slot == j) v[j] = -INFINITY;
    if (lane == k) { keepv = bv; keepi = bi; }
  }
  const float tk = fmaxf(logf(keepv), -1000.0f) + 50.0f;
  float m = (lane < 50) ? tk : INFINITY;
  #pragma unroll
  for (int off = 1; off < 64; off <<= 1) m = fminf(m, __shfl_xor(m, off));
  const float shift = fmaxf(-m, 0.0f);
  if (lane < 50) {
    vals[b * 50 + lane] = tk + shift;
    idxs[b * 50 + lane] = keepi;
  }
}

// ---------------- w1 transpose: [1000][512][16] f32 -> [1000][16][512] bf16 -
__global__ __launch_bounds__(256) void w1t_kernel(const float* __restrict__ w1,
                                                  u16* __restrict__ w1t) {
  const int cin = blockIdx.x;
  const int t = threadIdx.x;
  __shared__ float is[512 * 17];
  const float* src = w1 + (size_t)cin * 8192;
  #pragma unroll
  for (int r = 0; r < 8; ++r) {
    const int f = r * 1024 + t * 4;
    const float4 v = *reinterpret_cast<const float4*>(src + f);
    const int co = f >> 4, s = f & 15;
    is[co * 17 + s + 0] = v.x;
    is[co * 17 + s + 1] = v.y;
    is[co * 17 + s + 2] = v.z;
    is[co * 17 + s + 3] = v.w;
  }
  __syncthreads();
  u16* dst = w1t + (size_t)cin * 8192;
  #pragma unroll
  for (int p = 0; p < 4; ++p) {
    const int i8 = (p * 256 + t) * 8;
    const int s = i8 >> 9, co = i8 & 511;
    union { u16 h[8]; s16x8 v; } pk;
    #pragma unroll
    for (int q = 0; q < 8; ++q) pk.h[q] = f2bf(is[(co + q) * 17 + s]);
    *reinterpret_cast<s16x8*>(dst + i8) = pk.v;
  }
}

// ---------------- w2/w3 transpose: [CIN][COUT][16] f32 -> [COUT][16][CIN] bf16
template <int CIN, int COUT>
__global__ __launch_bounds__(256) void wt_kernel(const float* __restrict__ w,
                                                 u16* __restrict__ wt) {
  const int o = blockIdx.x;
  const int t = threadIdx.x;
  __shared__ __align__(16) u16 tile[16 * CIN];
  for (int c = t; c < CIN; c += 256) {
    const float* src = w + ((size_t)c * COUT + o) * 16;
    #pragma unroll
    for (int q4 = 0; q4 < 4; ++q4) {
      const float4 v = *reinterpret_cast<const float4*>(src + q4 * 4);
      tile[(q4 * 4 + 0) * CIN + c] = f2bf(v.x);
      tile[(q4 * 4 + 1) * CIN + c] = f2bf(v.y);
      tile[(q4 * 4 + 2) * CIN + c] = f2bf(v.z);
      tile[(q4 * 4 + 3) * CIN + c] = f2bf(v.w);
    }
  }
  __syncthreads();
  u16* dst = wt + (size_t)o * 16 * CIN;
  for (int i8 = t * 8; i8 < 16 * CIN; i8 += 2048)
    *reinterpret_cast<s16x8*>(dst + i8) = *reinterpret_cast<const s16x8*>(tile + i8);
}

// ---------------- conv1: sparse gather, channels-last y1 [2048][16][512] ----
__global__ __launch_bounds__(256) void conv1_kernel(const float* __restrict__ vals,
                                                    const int* __restrict__ idxs,
                                                    const u16* __restrict__ w1t,
                                                    const float* __restrict__ b1,
                                                    u16* __restrict__ y1) {
  const int b = blockIdx.x;
  const int t = threadIdx.x;
  __shared__ float sval[50];
  __shared__ int sidx[50];
  if (t < 50) { sval[t] = vals[b * 50 + t]; sidx[t] = idxs[b * 50 + t]; }
  __syncthreads();
  const int co = (t & 63) * 8;
  const int s0 = t >> 6;
  float b8[8];
  #pragma unroll
  for (int q = 0; q < 8; ++q) b8[q] = b1[co + q];
  #pragma unroll
  for (int sp = 0; sp < 4; ++sp) {
    const int s = sp * 4 + s0;
    float acc[8] = {0.f, 0.f, 0.f, 0.f, 0.f, 0.f, 0.f, 0.f};
    for (int j = 0; j < 50; ++j) {
      const float v = sval[j];
      union { s16x8 v8; u16 h[8]; } w;
      w.v8 = *reinterpret_cast<const s16x8*>(w1t + (size_t)sidx[j] * 8192 + s * 512 + co);
      #pragma unroll
      for (int q = 0; q < 8; ++q) acc[q] = fmaf(v, bf2f(w.h[q]), acc[q]);
    }
    union { u16 h[8]; s16x8 v8; } o;
    #pragma unroll
    for (int q = 0; q < 8; ++q) o.h[q] = f2bf(acc[q] + b8[q]);
    *reinterpret_cast<s16x8*>(y1 + (size_t)b * 8192 + s * 512 + co) = o.v8;
  }
}

// ---------------- BN stats, channels-last [ROWS][C] (128 splits) ------------
__global__ __launch_bounds__(256) void bnstats_kernel(const u16* __restrict__ y,
                                                      float* __restrict__ sp,
                                                      float* __restrict__ sqp,
                                                      int C, int CB, int ROWS) {
  const int PB = CB >> 1;
  const int PR = 256 / PB;
  const int t = threadIdx.x;
  const int cp = t & (PB - 1);
  const int rl = t / PB;
  const int cbase = blockIdx.x * CB;
  const int split = blockIdx.y;
  const int RPB = ROWS >> 7;
  const u16* base = y + (size_t)split * RPB * C + cbase + 2 * cp;
  float s0 = 0.f, s1 = 0.f, q0 = 0.f, q1 = 0.f;
  for (int r = rl; r < RPB; r += PR) {
    const u32 raw = *reinterpret_cast<const u32*>(base + (size_t)r * C);
    const float a = bf2f((u16)(raw & 0xffffu));
    const float b = bf2f((u16)(raw >> 16));
    s0 += a; s1 += b;
    q0 = fmaf(a, a, q0); q1 = fmaf(b, b, q1);
  }
  __shared__ float4 arr[256];
  arr[t] = make_float4(s0, s1, q0, q1);
  __syncthreads();
  if (t < PB) {
    float4 acc = arr[t];
    for (int g = 1; g < PR; ++g) {
      const float4 v = arr[g * PB + t];
      acc.x += v.x; acc.y += v.y; acc.z += v.z; acc.w += v.w;
    }
    const int c = cbase + 2 * t;
    sp[split * C + c] = acc.x;
    sp[split * C + c + 1] = acc.y;
    sqp[split * C + c] = acc.z;
    sqp[split * C + c + 1] = acc.w;
  }
}

__global__ __launch_bounds__(256) void bnfin_kernel(const float* __restrict__ sp,
                                                    const float* __restrict__ sqp,
                                                    const float* __restrict__ g,
                                                    const float* __restrict__ be,
                                                    float* __restrict__ a,
                                                    float* __restrict__ bb,
                                                    int C, float inv) {
  const int c = blockIdx.x * 256 + threadIdx.x;
  if (c >= C) return;
  float s = 0.f, s2 = 0.f;
  for (int k = 0; k < 128; ++k) { s += sp[k * C + c]; s2 += sqp[k * C + c]; }
  const float m = s * inv;
  float var = fmaf(-m, m, s2 * inv);
  var = fmaxf(var, 0.f);
  const float r = 1.0f / sqrtf(var + 1e-5f);
  const float av = g[c] * r;
  a[c] = av;
  bb[c] = fmaf(-m, av, be[c]);
}

// ---------------- BN affine + tanh in place, channels-last ------------------
__global__ __launch_bounds__(256) void bnact_kernel(u16* __restrict__ y,
                                                    const float* __restrict__ a,
                                                    const float* __restrict__ bb,
                                                    int Cm1) {
  const size_t i = ((size_t)blockIdx.x * 256 + threadIdx.x) * 8;
  const int c = (int)i & Cm1;
  uint4 raw = *reinterpret_cast<uint4*>(y + i);
  float av[8], bv[8];
  *reinterpret_cast<float4*>(av) = *reinterpret_cast<const float4*>(a + c);
  *reinterpret_cast<float4*>(av + 4) = *reinterpret_cast<const float4*>(a + c + 4);
  *reinterpret_cast<float4*>(bv) = *reinterpret_cast<const float4*>(bb + c);
  *reinterpret_cast<float4*>(bv + 4) = *reinterpret_cast<const float4*>(bb + c + 4);
  u32 w[4] = {raw.x, raw.y, raw.z, raw.w};
  #pragma unroll
  for (int q = 0; q < 4; ++q) {
    const float lo = tanhf(fmaf(bf2f((u16)(w[q] & 0xffffu)), av[2 * q], bv[2 * q]));
    const float hi = tanhf(fmaf(bf2f((u16)(w[q] >> 16)), av[2 * q + 1], bv[2 * q + 1]));
    w[q] = (u32)f2bf(lo) | ((u32)f2bf(hi) << 16);
  }
  raw.x = w[0]; raw.y = w[1]; raw.z = w[2]; raw.w = w[3];
  *reinterpret_cast<uint4*>(y + i) = raw;
}

// ---------------- MFMA convT k=4 s=2 p=1, 2-phase pipelined -----------------
// in: [B][SIN*SIN][CIN] bf16 channels-last. wt: [COUT_W][16][CIN] bf16.
// out: [B][4*SIN*SIN][COUT_STORE] bf16, channel slice [o_gbase, o_gbase+grid.x*NB).
template <int SIN, int CIN, int WM, int WN, int MBATCH, int COUT_STORE>
__global__ __launch_bounds__(256) void convt_mfma(const u16* __restrict__ in,
                                                  const u16* __restrict__ wt,
                                                  const float* __restrict__ bias,
                                                  u16* __restrict__ outp,
                                                  int o_gbase) {
  constexpr int SS = SIN * SIN;
  constexpr int MB = MBATCH * SS;          // input rows per block
  constexpr int MFR = MB / (16 * WM);      // m-frags per wave
  constexpr int NB = WN * 16;              // out channels per block
  constexpr int LOGS = (SIN == 4) ? 2 : 3;
  constexpr int NPASS = MB / 32;           // staging passes (32 rows per pass)
  constexpr int NSTEP = CIN / 64;          // K steps
  constexpr int BUFW = (MB + 1) * 64;      // u16 per LDS buffer (row MB = zeros)
  constexpr int KYT[2][2] = {{1, 3}, {2, 0}};
  constexpr int DYT[2][2] = {{0, -1}, {0, 1}};
  static_assert(MB % 32 == 0, "staging");
  __shared__ __align__(16) u16 As[2 * BUFW];

  const int t = threadIdx.x;
  const int lane = t & 63;
  const int wave = t >> 6;
  const int wn = wave % WN;
  const int wm = wave / WN;
  const int l15 = lane & 15;
  const int kl = lane >> 4;
  const int bx = blockIdx.x;
  const int R0 = blockIdx.y * MB;

  // per-lane LDS byte offsets for the 9 shifts x MFR frags (swizzle pre-folded)
  int rb[9][MFR];
  #pragma unroll
  for (int m = 0; m < MFR; ++m) {
    const int r = wm * (MB / WM) + m * 16 + l15;
    const int bl = r >> (2 * LOGS);
    const int rr = r & (SS - 1);
    const int sy = rr >> LOGS, sx = rr & (SIN - 1);
    #pragma unroll
    for (int dyi = 0; dyi < 3; ++dyi)
      #pragma unroll
      for (int dxi = 0; dxi < 3; ++dxi) {
        const int ny = sy + dyi - 1, nx = sx + dxi - 1;
        const bool ok = (ny >= 0 && ny < SIN && nx >= 0 && nx < SIN);
        const int rp = ok ? ((bl << (2 * LOGS)) + (ny << LOGS) + nx) : MB;
        rb[dyi * 3 + dxi][m] = (rp << 7) | ((rp & 7) << 4);
      }
  }
  // zero the sentinel row of both buffers (never overwritten by staging)
  if (t < 8) {
    s16x8 z = {};
    *reinterpret_cast<s16x8*>(As + MB * 64 + t * 8) = z;
    *reinterpret_cast<s16x8*>(As + BUFW + MB * 64 + t * 8) = z;
  }

  f32x4 acc[2][2][MFR];
  #pragma unroll
  for (int py = 0; py < 2; ++py)
    #pragma unroll
    for (int px = 0; px < 2; ++px)
      #pragma unroll
      for (int m = 0; m < MFR; ++m) acc[py][px][m] = (f32x4){0.f, 0.f, 0.f, 0.f};

  const int ocol = o_gbase + bx * NB + wn * 16 + l15;
  const size_t wbase = (size_t)ocol * 16 * CIN + kl * 8;
  const int kl16 = kl * 16;

  // staging geometry: thread covers (row = p*32 + t>>3, 16B at col (t&7)*8)
  const int srow = t >> 3;
  const int scol = (t & 7) * 8;
  const u16* gsrc = in + (size_t)(R0 + srow) * CIN + scol;

  // prologue: prefetch K-step 0 into registers
  s16x8 sreg[NPASS];
  #pragma unroll
  for (int p = 0; p < NPASS; ++p)
    sreg[p] = *reinterpret_cast<const s16x8*>(gsrc + (size_t)p * 32 * CIN);

  int cur = 0;
  for (int s = 0; s < NSTEP; ++s) {
    // write staged regs into buf[cur] (XOR-swizzled rows)
    u16* dbuf = As + cur * BUFW;
    #pragma unroll
    for (int p = 0; p < NPASS; ++p) {
      const int row = p * 32 + srow;
      const int db = row * 128 + ((scol * 2) ^ ((row & 7) << 4));
      *reinterpret_cast<s16x8*>((char*)dbuf + db) = sreg[p];
    }
    // issue next K-step loads; they stay in flight across the barrier
    if (s + 1 < NSTEP) {
      const u16* gn = gsrc + (s + 1) * 64;
      #pragma unroll
      for (int p = 0; p < NPASS; ++p)
        sreg[p] = *reinterpret_cast<const s16x8*>(gn + (size_t)p * 32 * CIN);
    }
    lds_barrier();   // lgkmcnt(0) only; single barrier per step

    const int c0 = s * 64;
    const u16* Ab = As + cur * BUFW;
    #pragma unroll
    for (int kh = 0; kh < 2; ++kh) {
      const int koff = kh * 64 + kl16;
      const size_t kw = wbase + c0 + kh * 32;
      s16x8 bf[2][2][2][2];
      #pragma unroll
      for (int py = 0; py < 2; ++py)
        #pragma unroll
        for (int px = 0; px < 2; ++px)
          #pragma unroll
          for (int jy = 0; jy < 2; ++jy)
            #pragma unroll
            for (int jx = 0; jx < 2; ++jx) {
              const int tap = KYT[py][jy] * 4 + KYT[px][jx];
              bf[py][px][jy][jx] =
                  *reinterpret_cast<const s16x8*>(wt + kw + (size_t)tap * CIN);
            }
      __builtin_amdgcn_s_setprio(1);
      #pragma unroll
      for (int m = 0; m < MFR; ++m) {
        s16x8 af[9];
        #pragma unroll
        for (int s9 = 0; s9 < 9; ++s9)
          af[s9] = *reinterpret_cast<const s16x8*>((const char*)Ab + (rb[s9][m] ^ koff));
        #pragma unroll
        for (int py = 0; py < 2; ++py)
          #pragma unroll
          for (int px = 0; px < 2; ++px)
            #pragma unroll
            for (int jy = 0; jy < 2; ++jy)
              #pragma unroll
              for (int jx = 0; jx < 2; ++jx) {
                const int s9 = (DYT[py][jy] + 1) * 3 + (DYT[px][jx] + 1);
                acc[py][px][m] = __builtin_amdgcn_mfma_f32_16x16x32_bf16(
                    af[s9], bf[py][px][jy][jx], acc[py][px][m], 0, 0, 0);
              }
      }
      __builtin_amdgcn_s_setprio(0);
    }
    cur ^= 1;
  }

  const int cstore = bx * NB + wn * 16 + l15;
  const float bo = bias[ocol];
  const int B0 = blockIdx.y * MBATCH;
  #pragma unroll
  for (int m = 0; m < MFR; ++m)
    #pragma unroll
    for (int i = 0; i < 4; ++i) {
      const int r = wm * (MB / WM) + m * 16 + kl * 4 + i;
      const int bl = r >> (2 * LOGS);
      const int rr = r & (SS - 1);
      const int sy = rr >> LOGS, sx = rr & (SIN - 1);
      const size_t ob = (size_t)(B0 + bl) * 4 * SS;
      #pragma unroll
      for (int py = 0; py < 2; ++py)
        #pragma unroll
        for (int px = 0; px < 2; ++px) {
          const int od = (2 * sy + py) * (2 * SIN) + 2 * sx + px;
          outp[(ob + od) * COUT_STORE + cstore] = f2bf(acc[py][px][m][i] + bo);
        }
    }
}

// ---------------- conv4: fused BN-affine+tanh + convT(128->1) + sigmoid -----
__global__ __launch_bounds__(256) void conv4_kernel(const u16* __restrict__ h3c,
                                                    const float* __restrict__ ac,
                                                    const float* __restrict__ bc,
                                                    const float* __restrict__ w4,
                                                    const float* __restrict__ b4,
                                                    float* __restrict__ outp,
                                                    int cbase, int last) {
  const int b = blockIdx.x;
  const int t = threadIdx.x;
  __shared__ float wsh[32 * 16];
  __shared__ float is[32 * 257];
  for (int i = t; i < 512; i += 256) wsh[i] = w4[cbase * 16 + i];
  const int cq = (t & 3) * 8;
  float av[8], bv[8];
  *reinterpret_cast<float4*>(av)     = *reinterpret_cast<const float4*>(ac + cq);
  *reinterpret_cast<float4*>(av + 4) = *reinterpret_cast<const float4*>(ac + cq + 4);
  *reinterpret_cast<float4*>(bv)     = *reinterpret_cast<const float4*>(bc + cq);
  *reinterpret_cast<float4*>(bv + 4) = *reinterpret_cast<const float4*>(bc + cq + 4);
  #pragma unroll
  for (int p = 0; p < 4; ++p) {
    const int idx8 = p * 256 + t;
    const int s = idx8 >> 2;
    union { s16x8 v8; u16 h[8]; } r;
    r.v8 = *reinterpret_cast<const s16x8*>(h3c + ((size_t)b * 256 + s) * 32 + cq);
    #pragma unroll
    for (int q = 0; q < 8; ++q)
      is[(cq + q) * 257 + s] = tanhf(fmaf(bf2f(r.h[q]), av[q], bv[q]));
  }
  __syncthreads();
  float acc[4] = {0.f, 0.f, 0.f, 0.f};
  const int ox = t & 31;
  const int oy0 = t >> 5;
  for (int c = 0; c < 32; ++c) {
    #pragma unroll
    for (int k = 0; k < 4; ++k) {
      const int oy = oy0 + 8 * k;
      #pragma unroll
      for (int jy = 0; jy < 2; ++jy) {
        const int ky = 2 * jy + 1 - (oy & 1);
        const int iyn = oy + 1 - ky;
        if ((unsigned)iyn < 32u) {
          const int iy = iyn >> 1;
          #pragma unroll
          for (int jx = 0; jx < 2; ++jx) {
            const int kx = 2 * jx + 1 - (ox & 1);
            const int ixn = ox + 1 - kx;
            if ((unsigned)ixn < 32u) {
              const int ix = ixn >> 1;
              acc[k] = fmaf(is[c * 257 + iy * 16 + ix], wsh[c * 16 + ky * 4 + kx], acc[k]);
            }
          }
        }
      }
    }
  }
  #pragma unroll
  for (int k = 0; k < 4; ++k) {
    const int oy = oy0 + 8 * k;
    const size_t ob = (size_t)b * 1024 + oy * 32 + ox;
    const float base = (cbase == 0) ? b4[0] : outp[ob];
    const float v = base + acc[k];
    outp[ob] = last ? (1.0f / (1.0f + expf(-v))) : v;
  }
}

// ----------------------------------------------------------------------------
extern "C" void kernel_launch(void* const* d_in, const int* in_sizes, int n_in,
                              void* d_out, int out_size, void* d_ws, size_t ws_size,
                              hipStream_t stream) {
  (void)in_sizes; (void)n_in; (void)out_size; (void)ws_size;
  const float* x   = (const float*)d_in[0];
  const float* w1  = (const float*)d_in[1];
  const float* b1  = (const float*)d_in[2];
  const float* g1  = (const float*)d_in[3];
  const float* be1 = (const float*)d_in[4];
  const float* w2  = (const float*)d_in[5];
  const float* b2  = (const float*)d_in[6];
  const float* g2  = (const float*)d_in[7];
  const float* be2 = (const float*)d_in[8];
  const float* w3  = (const float*)d_in[9];
  const float* b3  = (const float*)d_in[10];
  const float* g3  = (const float*)d_in[11];
  const float* be3 = (const float*)d_in[12];
  const float* w4  = (const float*)d_in[13];
  const float* b4  = (const float*)d_in[14];

  char* ws = (char*)d_ws;
  u16*   y2   = (u16*)(ws + 0);
  u16*   y1   = (u16*)(ws + 67108864);
  u16*   w3t  = (u16*)(ws + 67108864);    // after conv2 (aliases y1)
  u16*   y3c  = (u16*)(ws + 100663296);
  u16*   w1t  = (u16*)(ws + 100663296);   // dead after conv1 (aliases y3c)
  u16*   w2t  = (u16*)(ws + 117047296);   // dead after conv2 (aliases y3c)
  float* vals = (float*)(ws + 134217728);
  int*   idxs = (int*)(ws + 134627328);
  float* sp   = (float*)(ws + 134217728); // after conv1 (aliases vals)
  float* sqp  = (float*)(ws + 134479872);
  float* ac   = (float*)(ws + 134742016);
  float* bc   = (float*)(ws + 134744064);
  float* outp = (float*)d_out;

  // precomputes + truncation vector
  w1t_kernel<<<1000, 256, 0, stream>>>(w1, w1t);
  wt_kernel<512, 256><<<256, 256, 0, stream>>>(w2, w2t);
  topk_kernel<<<512, 256, 0, stream>>>(x, vals, idxs);

  // layer 1
  conv1_kernel<<<2048, 256, 0, stream>>>(vals, idxs, w1t, b1, y1);
  bnstats_kernel<<<dim3(4, 128), 256, 0, stream>>>(y1, sp, sqp, 512, 128, 32768);
  bnfin_kernel<<<2, 256, 0, stream>>>(sp, sqp, g1, be1, ac, bc, 512, 1.0f / 32768.0f);
  bnact_kernel<<<8192, 256, 0, stream>>>(y1, ac, bc, 511);

  // layer 2: MFMA convT 512->256, 4x4 -> 8x8 (MBATCH=2 -> 4096 blocks)
  convt_mfma<4, 512, 1, 4, 2, 256><<<dim3(4, 1024), 256, 0, stream>>>(y1, w2t, b2, y2, 0);
  wt_kernel<256, 128><<<128, 256, 0, stream>>>(w3, w3t);
  bnstats_kernel<<<dim3(2, 128), 256, 0, stream>>>(y2, sp, sqp, 256, 128, 131072);
  bnfin_kernel<<<1, 256, 0, stream>>>(sp, sqp, g2, be2, ac, bc, 256, 1.0f / 131072.0f);
  bnact_kernel<<<16384, 256, 0, stream>>>(y2, ac, bc, 255);

  // layer 3+4: MFMA convT 256->128 in 4 chunks of 32 oc (MBATCH=1 -> 2048 blocks);
  // BN-affine+tanh fused into conv4, which accumulates into d_out
  for (int ch = 0; ch < 4; ++ch) {
    const int cb = ch * 32;
    convt_mfma<8, 256, 2, 2, 1, 32><<<dim3(1, 2048), 256, 0, stream>>>(y2, w3t, b3, y3c, cb);
    bnstats_kernel<<<dim3(1, 128), 256, 0, stream>>>(y3c, sp, sqp, 32, 32, 524288);
    bnfin_kernel<<<1, 256, 0, stream>>>(sp, sqp, g3 + cb, be3 + cb, ac, bc, 32, 1.0f / 524288.0f);
    conv4_kernel<<<2048, 256, 0, stream>>>(y3c, ac, bc, w4, b4, outp, cb, ch == 3);
  }
}

// Round 8
// 1530.286 us; speedup vs baseline: 1.1951x; 1.1951x over previous
//
#include <hip/hip_runtime.h>
#include <cstdint>
#include <cstddef>

// ----------------------------------------------------------------------------
// R8: un-confounded pipeline fix. R6 geometry (MFR=4) + R7 single-lgkm-barrier
// A-pipeline + B-loads issued before barrier / bf1 before kh0 MFMAs (hide L2
// latency under compute), BN-stats fused into convt epilogues.
// Workspace (max end 135,073,792 — proven):
//   y2   @ 0           64MB  [2048][64][256] bf16
//   y1   @ 67108864    32MB  (dead after conv2)
//   w3t  @ 67108864    1MB   (written after conv2, aliases y1)
//   y3c  @ 100663296   32MB  (written at conv3)
//   w1t  @ 100663296   16MB  (dead after conv1, aliases y3c)
//   sp2  @ 100663296 +512KB, sqp2 @ 101187584 (conv2 epi -> bnfin2, dead before conv3)
//   w2t  @ 117047296   4MB   (dead after conv2)
//   vals @ 134217728, idxs @ 134627328 (dead after conv1)
//   sp1/sp3 @ 134217728 (256KB), sqp1/sqp3 @ 134479872, ac @ 134742016, bc @ 134744064
// ----------------------------------------------------------------------------

typedef unsigned short u16;
typedef unsigned int u32;
typedef __attribute__((ext_vector_type(8))) short s16x8;   // 8 bf16 (4 VGPR)
typedef __attribute__((ext_vector_type(4))) float f32x4;

static __device__ __forceinline__ float bf2f(u16 u) {
  union { u32 i; float f; } v; v.i = ((u32)u) << 16; return v.f;
}
static __device__ __forceinline__ u16 f2bf(float f) {  // RNE
  union { float f; u32 i; } v; v.f = f;
  const u32 r = v.i + 0x7fffu + ((v.i >> 16) & 1u);
  return (u16)(r >> 16);
}
// barrier that waits only LDS ops -> in-flight global loads cross it
static __device__ __forceinline__ void lds_barrier() {
  asm volatile("s_waitcnt lgkmcnt(0)" ::: "memory");
  __builtin_amdgcn_s_barrier();
}

// ---------------- top-k(50): one wave per row, all in registers -------------
__global__ __launch_bounds__(256) void topk_kernel(const float* __restrict__ x,
                                                   float* __restrict__ vals,
                                                   int* __restrict__ idxs) {
  const int lane = threadIdx.x & 63;
  const int b = blockIdx.x * 4 + (threadIdx.x >> 6);
  float v[16];
  #pragma unroll
  for (int j = 0; j < 16; ++j) {
    const int idx = lane + 64 * j;
    v[j] = (idx < 1000) ? x[(size_t)b * 1000 + idx] : -INFINITY;
  }
  float keepv = 1.0f;
  int keepi = 0;
  for (int k = 0; k < 50; ++k) {
    float bv = v[0]; int bj = 0;
    #pragma unroll
    for (int j = 1; j < 16; ++j)
      if (v[j] > bv) { bv = v[j]; bj = j; }
    int bi = lane + 64 * bj;
    #pragma unroll
    for (int off = 1; off < 64; off <<= 1) {
      const float ov = __shfl_xor(bv, off);
      const int oi = __shfl_xor(bi, off);
      if (ov > bv || (ov == bv && oi < bi)) { bv = ov; bi = oi; }
    }
    const int slot = bi >> 6;
    const bool own = (lane == (bi & 63));
    #pragma unroll
    for (int j = 0; j < 16; ++j)
      if (own && slot == j) v[j] = -INFINITY;
    if (lane == k) { keepv = bv; keepi = bi; }
  }
  const float tk = fmaxf(logf(keepv), -1000.0f) + 50.0f;
  float m = (lane < 50) ? tk : INFINITY;
  #pragma unroll
  for (int off = 1; off < 64; off <<= 1) m = fminf(m, __shfl_xor(m, off));
  const float shift = fmaxf(-m, 0.0f);
  if (lane < 50) {
    vals[b * 50 + lane] = tk + shift;
    idxs[b * 50 + lane] = keepi;
  }
}

// ---------------- w1 transpose: [1000][512][16] f32 -> [1000][16][512] bf16 -
__global__ __launch_bounds__(256) void w1t_kernel(const float* __restrict__ w1,
                                                  u16* __restrict__ w1t) {
  const int cin = blockIdx.x;
  const int t = threadIdx.x;
  __shared__ float is[512 * 17];
  const float* src = w1 + (size_t)cin * 8192;
  #pragma unroll
  for (int r = 0; r < 8; ++r) {
    const int f = r * 1024 + t * 4;
    const float4 v = *reinterpret_cast<const float4*>(src + f);
    const int co = f >> 4, s = f & 15;
    is[co * 17 + s + 0] = v.x;
    is[co * 17 + s + 1] = v.y;
    is[co * 17 + s + 2] = v.z;
    is[co * 17 + s + 3] = v.w;
  }
  __syncthreads();
  u16* dst = w1t + (size_t)cin * 8192;
  #pragma unroll
  for (int p = 0; p < 4; ++p) {
    const int i8 = (p * 256 + t) * 8;
    const int s = i8 >> 9, co = i8 & 511;
    union { u16 h[8]; s16x8 v; } pk;
    #pragma unroll
    for (int q = 0; q < 8; ++q) pk.h[q] = f2bf(is[(co + q) * 17 + s]);
    *reinterpret_cast<s16x8*>(dst + i8) = pk.v;
  }
}

// ---------------- w2/w3 transpose: [CIN][COUT][16] f32 -> [COUT][16][CIN] bf16
template <int CIN, int COUT>
__global__ __launch_bounds__(256) void wt_kernel(const float* __restrict__ w,
                                                 u16* __restrict__ wt) {
  const int o = blockIdx.x;
  const int t = threadIdx.x;
  __shared__ __align__(16) u16 tile[16 * CIN];
  for (int c = t; c < CIN; c += 256) {
    const float* src = w + ((size_t)c * COUT + o) * 16;
    #pragma unroll
    for (int q4 = 0; q4 < 4; ++q4) {
      const float4 v = *reinterpret_cast<const float4*>(src + q4 * 4);
      tile[(q4 * 4 + 0) * CIN + c] = f2bf(v.x);
      tile[(q4 * 4 + 1) * CIN + c] = f2bf(v.y);
      tile[(q4 * 4 + 2) * CIN + c] = f2bf(v.z);
      tile[(q4 * 4 + 3) * CIN + c] = f2bf(v.w);
    }
  }
  __syncthreads();
  u16* dst = wt + (size_t)o * 16 * CIN;
  for (int i8 = t * 8; i8 < 16 * CIN; i8 += 2048)
    *reinterpret_cast<s16x8*>(dst + i8) = *reinterpret_cast<const s16x8*>(tile + i8);
}

// ---------------- conv1: sparse gather, channels-last y1 [2048][16][512] ----
__global__ __launch_bounds__(256) void conv1_kernel(const float* __restrict__ vals,
                                                    const int* __restrict__ idxs,
                                                    const u16* __restrict__ w1t,
                                                    const float* __restrict__ b1,
                                                    u16* __restrict__ y1) {
  const int b = blockIdx.x;
  const int t = threadIdx.x;
  __shared__ float sval[50];
  __shared__ int sidx[50];
  if (t < 50) { sval[t] = vals[b * 50 + t]; sidx[t] = idxs[b * 50 + t]; }
  __syncthreads();
  const int co = (t & 63) * 8;
  const int s0 = t >> 6;
  float b8[8];
  #pragma unroll
  for (int q = 0; q < 8; ++q) b8[q] = b1[co + q];
  #pragma unroll
  for (int sp = 0; sp < 4; ++sp) {
    const int s = sp * 4 + s0;
    float acc[8] = {0.f, 0.f, 0.f, 0.f, 0.f, 0.f, 0.f, 0.f};
    for (int j = 0; j < 50; ++j) {
      const float v = sval[j];
      union { s16x8 v8; u16 h[8]; } w;
      w.v8 = *reinterpret_cast<const s16x8*>(w1t + (size_t)sidx[j] * 8192 + s * 512 + co);
      #pragma unroll
      for (int q = 0; q < 8; ++q) acc[q] = fmaf(v, bf2f(w.h[q]), acc[q]);
    }
    union { u16 h[8]; s16x8 v8; } o;
    #pragma unroll
    for (int q = 0; q < 8; ++q) o.h[q] = f2bf(acc[q] + b8[q]);
    *reinterpret_cast<s16x8*>(y1 + (size_t)b * 8192 + s * 512 + co) = o.v8;
  }
}

// ---------------- BN stats (y1 only), channels-last [ROWS][C], 128 splits ---
__global__ __launch_bounds__(256) void bnstats_kernel(const u16* __restrict__ y,
                                                      float* __restrict__ sp,
                                                      float* __restrict__ sqp,
                                                      int C, int CB, int ROWS) {
  const int PB = CB >> 1;
  const int PR = 256 / PB;
  const int t = threadIdx.x;
  const int cp = t & (PB - 1);
  const int rl = t / PB;
  const int cbase = blockIdx.x * CB;
  const int split = blockIdx.y;
  const int RPB = ROWS >> 7;
  const u16* base = y + (size_t)split * RPB * C + cbase + 2 * cp;
  float s0 = 0.f, s1 = 0.f, q0 = 0.f, q1 = 0.f;
  for (int r = rl; r < RPB; r += PR) {
    const u32 raw = *reinterpret_cast<const u32*>(base + (size_t)r * C);
    const float a = bf2f((u16)(raw & 0xffffu));
    const float b = bf2f((u16)(raw >> 16));
    s0 += a; s1 += b;
    q0 = fmaf(a, a, q0); q1 = fmaf(b, b, q1);
  }
  __shared__ float4 arr[256];
  arr[t] = make_float4(s0, s1, q0, q1);
  __syncthreads();
  if (t < PB) {
    float4 acc = arr[t];
    for (int g = 1; g < PR; ++g) {
      const float4 v = arr[g * PB + t];
      acc.x += v.x; acc.y += v.y; acc.z += v.z; acc.w += v.w;
    }
    const int c = cbase + 2 * t;
    sp[split * C + c] = acc.x;
    sp[split * C + c + 1] = acc.y;
    sqp[split * C + c] = acc.z;
    sqp[split * C + c + 1] = acc.w;
  }
}

// ---------------- BN finalize, variable split count / channel count ---------
__global__ __launch_bounds__(256) void bnfin_kernel(const float* __restrict__ sp,
                                                    const float* __restrict__ sqp,
                                                    const float* __restrict__ g,
                                                    const float* __restrict__ be,
                                                    float* __restrict__ a,
                                                    float* __restrict__ bb,
                                                    int logC, int SPLITS, float inv) {
  const int t = threadIdx.x;
  const int C = 1 << logC;
  const int lc = t & (C - 1);
  int PARTS = 256 >> logC;
  if (PARTS == 0) PARTS = 1;
  const int part = t >> logC;   // 0 when C >= 256
  const int chunk = SPLITS / PARTS;
  const int c = (blockIdx.x << 8) + lc;
  float s = 0.f, s2 = 0.f;
  for (int k = part * chunk; k < (part + 1) * chunk; ++k) {
    s += sp[(size_t)k * C + c];
    s2 += sqp[(size_t)k * C + c];
  }
  __shared__ float rs[256], rq[256];
  rs[t] = s; rq[t] = s2;
  __syncthreads();
  if (part == 0) {
    for (int p = 1; p < PARTS; ++p) {
      s += rs[(p << logC) + lc];
      s2 += rq[(p << logC) + lc];
    }
    const float m = s * inv;
    float var = fmaf(-m, m, s2 * inv);
    var = fmaxf(var, 0.f);
    const float r = 1.0f / sqrtf(var + 1e-5f);
    const float av = g[c] * r;
    a[c] = av;
    bb[c] = fmaf(-m, av, be[c]);
  }
}

// ---------------- BN affine + tanh in place, channels-last ------------------
__global__ __launch_bounds__(256) void bnact_kernel(u16* __restrict__ y,
                                                    const float* __restrict__ a,
                                                    const float* __restrict__ bb,
                                                    int Cm1) {
  const size_t i = ((size_t)blockIdx.x * 256 + threadIdx.x) * 8;
  const int c = (int)i & Cm1;
  uint4 raw = *reinterpret_cast<uint4*>(y + i);
  float av[8], bv[8];
  *reinterpret_cast<float4*>(av) = *reinterpret_cast<const float4*>(a + c);
  *reinterpret_cast<float4*>(av + 4) = *reinterpret_cast<const float4*>(a + c + 4);
  *reinterpret_cast<float4*>(bv) = *reinterpret_cast<const float4*>(bb + c);
  *reinterpret_cast<float4*>(bv + 4) = *reinterpret_cast<const float4*>(bb + c + 4);
  u32 w[4] = {raw.x, raw.y, raw.z, raw.w};
  #pragma unroll
  for (int q = 0; q < 4; ++q) {
    const float lo = tanhf(fmaf(bf2f((u16)(w[q] & 0xffffu)), av[2 * q], bv[2 * q]));
    const float hi = tanhf(fmaf(bf2f((u16)(w[q] >> 16)), av[2 * q + 1], bv[2 * q + 1]));
    w[q] = (u32)f2bf(lo) | ((u32)f2bf(hi) << 16);
  }
  raw.x = w[0]; raw.y = w[1]; raw.z = w[2]; raw.w = w[3];
  *reinterpret_cast<uint4*>(y + i) = raw;
}

// ---------------- MFMA convT k=4 s=2 p=1, pipelined + fused BN stats --------
// in: [B][SIN*SIN][CIN] bf16 channels-last. wt: [COUT_W][16][CIN] bf16.
// out: [B][4*SIN*SIN][COUT_STORE] bf16. Epilogue also writes per-block
// per-channel (sum, sumsq) partials: spp/sqpp[[gridDim.y*WM][COUT_STORE]].
template <int SIN, int CIN, int WM, int WN, int MBATCH, int COUT_STORE>
__global__ __launch_bounds__(256) void convt_mfma(const u16* __restrict__ in,
                                                  const u16* __restrict__ wt,
                                                  const float* __restrict__ bias,
                                                  u16* __restrict__ outp,
                                                  float* __restrict__ spp,
                                                  float* __restrict__ sqpp,
                                                  int o_gbase) {
  constexpr int SS = SIN * SIN;
  constexpr int MB = MBATCH * SS;          // input rows per block
  constexpr int MFR = MB / (16 * WM);      // m-frags per wave
  constexpr int NB = WN * 16;              // out channels per block
  constexpr int LOGS = (SIN == 4) ? 2 : 3;
  constexpr int NPASS = MB / 32;           // staging passes (32 rows per pass)
  constexpr int NSTEP = CIN / 64;          // K steps
  constexpr int BUFW = (MB + 1) * 64;      // u16 per buffer (row MB = zeros)
  constexpr int KYT[2][2] = {{1, 3}, {2, 0}};
  constexpr int DYT[2][2] = {{0, -1}, {0, 1}};
  static_assert(MB % 32 == 0, "staging");
  __shared__ __align__(16) u16 As[2 * BUFW];

  const int t = threadIdx.x;
  const int lane = t & 63;
  const int wave = t >> 6;
  const int wn = wave % WN;
  const int wm = wave / WN;
  const int l15 = lane & 15;
  const int kl = lane >> 4;
  const int bx = blockIdx.x;
  const int R0 = blockIdx.y * MB;

  // per-lane LDS byte offsets for the 9 shifts x MFR frags (swizzle pre-folded)
  int rb[9][MFR];
  #pragma unroll
  for (int m = 0; m < MFR; ++m) {
    const int r = wm * (MB / WM) + m * 16 + l15;
    const int bl = r >> (2 * LOGS);
    const int rr = r & (SS - 1);
    const int sy = rr >> LOGS, sx = rr & (SIN - 1);
    #pragma unroll
    for (int dyi = 0; dyi < 3; ++dyi)
      #pragma unroll
      for (int dxi = 0; dxi < 3; ++dxi) {
        const int ny = sy + dyi - 1, nx = sx + dxi - 1;
        const bool ok = (ny >= 0 && ny < SIN && nx >= 0 && nx < SIN);
        const int rp = ok ? ((bl << (2 * LOGS)) + (ny << LOGS) + nx) : MB;
        rb[dyi * 3 + dxi][m] = (rp << 7) | ((rp & 7) << 4);
      }
  }
  if (t < 8) {  // zero the sentinel row of both buffers
    s16x8 z = {};
    *reinterpret_cast<s16x8*>(As + MB * 64 + t * 8) = z;
    *reinterpret_cast<s16x8*>(As + BUFW + MB * 64 + t * 8) = z;
  }

  f32x4 acc[2][2][MFR];
  #pragma unroll
  for (int py = 0; py < 2; ++py)
    #pragma unroll
    for (int px = 0; px < 2; ++px)
      #pragma unroll
      for (int m = 0; m < MFR; ++m) acc[py][px][m] = (f32x4){0.f, 0.f, 0.f, 0.f};

  const int ocol = o_gbase + bx * NB + wn * 16 + l15;
  const size_t wbase = (size_t)ocol * 16 * CIN + kl * 8;
  const int kl16 = kl * 16;

  // staging geometry: thread covers (row = p*32 + t>>3, 16B at col (t&7)*8)
  const int srow = t >> 3;
  const int scol = (t & 7) * 8;
  const u16* gsrc = in + (size_t)(R0 + srow) * CIN + scol;

  // prologue: prefetch K-step 0 A into registers
  s16x8 sreg[NPASS];
  #pragma unroll
  for (int p = 0; p < NPASS; ++p)
    sreg[p] = *reinterpret_cast<const s16x8*>(gsrc + (size_t)p * 32 * CIN);

  int cur = 0;
  for (int s = 0; s < NSTEP; ++s) {
    // write staged A regs into buf[cur] (XOR-swizzled rows)
    u16* dbuf = As + cur * BUFW;
    #pragma unroll
    for (int p = 0; p < NPASS; ++p) {
      const int row = p * 32 + srow;
      const int db = row * 128 + ((scol * 2) ^ ((row & 7) << 4));
      *reinterpret_cast<s16x8*>((char*)dbuf + db) = sreg[p];
    }
    const int c0 = s * 64;
    // kh0 B-frags: pure global loads, issued BEFORE the barrier so L2 latency
    // hides under the LDS-write drain.
    s16x8 bf0[2][2][2][2];
    {
      const size_t kw = wbase + c0;
      #pragma unroll
      for (int py = 0; py < 2; ++py)
        #pragma unroll
        for (int px = 0; px < 2; ++px)
          #pragma unroll
          for (int jy = 0; jy < 2; ++jy)
            #pragma unroll
            for (int jx = 0; jx < 2; ++jx) {
              const int tap = KYT[py][jy] * 4 + KYT[px][jx];
              bf0[py][px][jy][jx] =
                  *reinterpret_cast<const s16x8*>(wt + kw + (size_t)tap * CIN);
            }
    }
    // next K-step A prefetch (stays in flight across the barrier)
    if (s + 1 < NSTEP) {
      const u16* gn = gsrc + (s + 1) * 64;
      #pragma unroll
      for (int p = 0; p < NPASS; ++p)
        sreg[p] = *reinterpret_cast<const s16x8*>(gn + (size_t)p * 32 * CIN);
    }
    lds_barrier();   // lgkmcnt(0) only; single barrier per K-step

    const u16* Ab = As + cur * BUFW;
    // kh1 B-frags issued before kh0 compute: latency hides under kh0 MFMAs.
    s16x8 bf1[2][2][2][2];
    {
      const size_t kw = wbase + c0 + 32;
      #pragma unroll
      for (int py = 0; py < 2; ++py)
        #pragma unroll
        for (int px = 0; px < 2; ++px)
          #pragma unroll
          for (int jy = 0; jy < 2; ++jy)
            #pragma unroll
            for (int jx = 0; jx < 2; ++jx) {
              const int tap = KYT[py][jy] * 4 + KYT[px][jx];
              bf1[py][px][jy][jx] =
                  *reinterpret_cast<const s16x8*>(wt + kw + (size_t)tap * CIN);
            }
    }
    // kh0 compute
    {
      const int koff = kl16;
      __builtin_amdgcn_s_setprio(1);
      #pragma unroll
      for (int m = 0; m < MFR; ++m) {
        s16x8 af[9];
        #pragma unroll
        for (int s9 = 0; s9 < 9; ++s9)
          af[s9] = *reinterpret_cast<const s16x8*>((const char*)Ab + (rb[s9][m] ^ koff));
        #pragma unroll
        for (int py = 0; py < 2; ++py)
          #pragma unroll
          for (int px = 0; px < 2; ++px)
            #pragma unroll
            for (int jy = 0; jy < 2; ++jy)
              #pragma unroll
              for (int jx = 0; jx < 2; ++jx) {
                const int s9 = (DYT[py][jy] + 1) * 3 + (DYT[px][jx] + 1);
                acc[py][px][m] = __builtin_amdgcn_mfma_f32_16x16x32_bf16(
                    af[s9], bf0[py][px][jy][jx], acc[py][px][m], 0, 0, 0);
              }
      }
      __builtin_amdgcn_s_setprio(0);
    }
    // kh1 compute
    {
      const int koff = 64 + kl16;
      __builtin_amdgcn_s_setprio(1);
      #pragma unroll
      for (int m = 0; m < MFR; ++m) {
        s16x8 af[9];
        #pragma unroll
        for (int s9 = 0; s9 < 9; ++s9)
          af[s9] = *reinterpret_cast<const s16x8*>((const char*)Ab + (rb[s9][m] ^ koff));
        #pragma unroll
        for (int py = 0; py < 2; ++py)
          #pragma unroll
          for (int px = 0; px < 2; ++px)
            #pragma unroll
            for (int jy = 0; jy < 2; ++jy)
              #pragma unroll
              for (int jx = 0; jx < 2; ++jx) {
                const int s9 = (DYT[py][jy] + 1) * 3 + (DYT[px][jx] + 1);
                acc[py][px][m] = __builtin_amdgcn_mfma_f32_16x16x32_bf16(
                    af[s9], bf1[py][px][jy][jx], acc[py][px][m], 0, 0, 0);
              }
      }
      __builtin_amdgcn_s_setprio(0);
    }
    cur ^= 1;
  }

  // epilogue: store + fused per-channel BN partials (fp32, pre-rounding)
  const int cstore = bx * NB + wn * 16 + l15;
  const float bo = bias[ocol];
  const int B0 = blockIdx.y * MBATCH;
  float s_ = 0.f, q_ = 0.f;
  #pragma unroll
  for (int m = 0; m < MFR; ++m)
    #pragma unroll
    for (int i = 0; i < 4; ++i) {
      const int r = wm * (MB / WM) + m * 16 + kl * 4 + i;
      const int bl = r >> (2 * LOGS);
      const int rr = r & (SS - 1);
      const int sy = rr >> LOGS, sx = rr & (SIN - 1);
      const size_t ob = (size_t)(B0 + bl) * 4 * SS;
      #pragma unroll
      for (int py = 0; py < 2; ++py)
        #pragma unroll
        for (int px = 0; px < 2; ++px) {
          const int od = (2 * sy + py) * (2 * SIN) + 2 * sx + px;
          const float v = acc[py][px][m][i] + bo;
          s_ += v;
          q_ = fmaf(v, v, q_);
          outp[(ob + od) * COUT_STORE + cstore] = f2bf(v);
        }
    }
  s_ += __shfl_xor(s_, 16);
  q_ += __shfl_xor(q_, 16);
  s_ += __shfl_xor(s_, 32);
  q_ += __shfl_xor(q_, 32);
  if (lane < 16) {
    const int split = blockIdx.y * WM + wm;
    spp[(size_t)split * COUT_STORE + cstore] = s_;
    sqpp[(size_t)split * COUT_STORE + cstore] = q_;
  }
}

// ---------------- conv4: fused BN-affine+tanh + convT(128->1) + sigmoid -----
__global__ __launch_bounds__(256) void conv4_kernel(const u16* __restrict__ h3c,
                                                    const float* __restrict__ ac,
                                                    const float* __restrict__ bc,
                                                    const float* __restrict__ w4,
                                                    const float* __restrict__ b4,
                                                    float* __restrict__ outp,
                                                    int cbase, int last) {
  const int b = blockIdx.x;
  const int t = threadIdx.x;
  __shared__ float wsh[32 * 16];
  __shared__ float is[32 * 257];
  for (int i = t; i < 512; i += 256) wsh[i] = w4[cbase * 16 + i];
  const int cq = (t & 3) * 8;
  float av[8], bv[8];
  *reinterpret_cast<float4*>(av)     = *reinterpret_cast<const float4*>(ac + cq);
  *reinterpret_cast<float4*>(av + 4) = *reinterpret_cast<const float4*>(ac + cq + 4);
  *reinterpret_cast<float4*>(bv)     = *reinterpret_cast<const float4*>(bc + cq);
  *reinterpret_cast<float4*>(bv + 4) = *reinterpret_cast<const float4*>(bc + cq + 4);
  #pragma unroll
  for (int p = 0; p < 4; ++p) {
    const int idx8 = p * 256 + t;
    const int s = idx8 >> 2;
    union { s16x8 v8; u16 h[8]; } r;
    r.v8 = *reinterpret_cast<const s16x8*>(h3c + ((size_t)b * 256 + s) * 32 + cq);
    #pragma unroll
    for (int q = 0; q < 8; ++q)
      is[(cq + q) * 257 + s] = tanhf(fmaf(bf2f(r.h[q]), av[q], bv[q]));
  }
  __syncthreads();
  float acc[4] = {0.f, 0.f, 0.f, 0.f};
  const int ox = t & 31;
  const int oy0 = t >> 5;
  for (int c = 0; c < 32; ++c) {
    #pragma unroll
    for (int k = 0; k < 4; ++k) {
      const int oy = oy0 + 8 * k;
      #pragma unroll
      for (int jy = 0; jy < 2; ++jy) {
        const int ky = 2 * jy + 1 - (oy & 1);
        const int iyn = oy + 1 - ky;
        if ((unsigned)iyn < 32u) {
          const int iy = iyn >> 1;
          #pragma unroll
          for (int jx = 0; jx < 2; ++jx) {
            const int kx = 2 * jx + 1 - (ox & 1);
            const int ixn = ox + 1 - kx;
            if ((unsigned)ixn < 32u) {
              const int ix = ixn >> 1;
              acc[k] = fmaf(is[c * 257 + iy * 16 + ix], wsh[c * 16 + ky * 4 + kx], acc[k]);
            }
          }
        }
      }
    }
  }
  #pragma unroll
  for (int k = 0; k < 4; ++k) {
    const int oy = oy0 + 8 * k;
    const size_t ob = (size_t)b * 1024 + oy * 32 + ox;
    const float base = (cbase == 0) ? b4[0] : outp[ob];
    const float v = base + acc[k];
    outp[ob] = last ? (1.0f / (1.0f + expf(-v))) : v;
  }
}

// ----------------------------------------------------------------------------
extern "C" void kernel_launch(void* const* d_in, const int* in_sizes, int n_in,
                              void* d_out, int out_size, void* d_ws, size_t ws_size,
                              hipStream_t stream) {
  (void)in_sizes; (void)n_in; (void)out_size; (void)ws_size;
  const float* x   = (const float*)d_in[0];
  const float* w1  = (const float*)d_in[1];
  const float* b1  = (const float*)d_in[2];
  const float* g1  = (const float*)d_in[3];
  const float* be1 = (const float*)d_in[4];
  const float* w2  = (const float*)d_in[5];
  const float* b2  = (const float*)d_in[6];
  const float* g2  = (const float*)d_in[7];
  const float* be2 = (const float*)d_in[8];
  const float* w3  = (const float*)d_in[9];
  const float* b3  = (const float*)d_in[10];
  const float* g3  = (const float*)d_in[11];
  const float* be3 = (const float*)d_in[12];
  const float* w4  = (const float*)d_in[13];
  const float* b4  = (const float*)d_in[14];

  char* ws = (char*)d_ws;
  u16*   y2   = (u16*)(ws + 0);
  u16*   y1   = (u16*)(ws + 67108864);
  u16*   w3t  = (u16*)(ws + 67108864);    // after conv2 (aliases y1)
  u16*   y3c  = (u16*)(ws + 100663296);
  u16*   w1t  = (u16*)(ws + 100663296);   // dead after conv1 (aliases y3c)
  float* sp2  = (float*)(ws + 100663296); // conv2 epi -> bnfin2 (dead pre-conv3)
  float* sqp2 = (float*)(ws + 101187584);
  u16*   w2t  = (u16*)(ws + 117047296);   // dead after conv2
  float* vals = (float*)(ws + 134217728);
  int*   idxs = (int*)(ws + 134627328);
  float* sp   = (float*)(ws + 134217728); // sp1 / sp3 (time-shared, aliases vals)
  float* sqp  = (float*)(ws + 134479872);
  float* ac   = (float*)(ws + 134742016);
  float* bc   = (float*)(ws + 134744064);
  float* outp = (float*)d_out;

  // precomputes + truncation vector
  w1t_kernel<<<1000, 256, 0, stream>>>(w1, w1t);
  wt_kernel<512, 256><<<256, 256, 0, stream>>>(w2, w2t);
  topk_kernel<<<512, 256, 0, stream>>>(x, vals, idxs);

  // layer 1
  conv1_kernel<<<2048, 256, 0, stream>>>(vals, idxs, w1t, b1, y1);
  bnstats_kernel<<<dim3(4, 128), 256, 0, stream>>>(y1, sp, sqp, 512, 128, 32768);
  bnfin_kernel<<<2, 256, 0, stream>>>(sp, sqp, g1, be1, ac, bc, 9, 128, 1.0f / 32768.0f);
  bnact_kernel<<<8192, 256, 0, stream>>>(y1, ac, bc, 511);

  // layer 2: MFMA convT 512->256 (R6 geometry, MFR=4) + fused stats
  convt_mfma<4, 512, 1, 4, 4, 256><<<dim3(4, 512), 256, 0, stream>>>(
      y1, w2t, b2, y2, sp2, sqp2, 0);
  wt_kernel<256, 128><<<128, 256, 0, stream>>>(w3, w3t);
  bnfin_kernel<<<1, 256, 0, stream>>>(sp2, sqp2, g2, be2, ac, bc, 8, 512, 1.0f / 131072.0f);
  bnact_kernel<<<16384, 256, 0, stream>>>(y2, ac, bc, 255);

  // layer 3+4: MFMA convT 256->128 in 4 chunks (R6 geometry, MFR=4) +
  // fused stats; conv4 applies BN-affine+tanh and accumulates into d_out
  for (int ch = 0; ch < 4; ++ch) {
    const int cb = ch * 32;
    convt_mfma<8, 256, 2, 2, 2, 32><<<dim3(1, 1024), 256, 0, stream>>>(
        y2, w3t, b3, y3c, sp, sqp, cb);
    bnfin_kernel<<<1, 256, 0, stream>>>(sp, sqp, g3 + cb, be3 + cb, ac, bc, 5, 2048,
                                        1.0f / 524288.0f);
    conv4_kernel<<<2048, 256, 0, stream>>>(y3c, ac, bc, w4, b4, outp, cb, ch == 3);
  }
}